// Round 1
// baseline (100.968 us; speedup 1.0000x reference)
//
#include <hip/hip_runtime.h>

#define FLOW_EPS 0.1f

// One thread per batch element. D=3, K=4 fixed.
// z <- ((z @ L) * d) @ U + b  per step; log_det += sum log|0.1 + w_ii|.
__global__ __launch_bounds__(256) void graphflow_kernel(
    const float* __restrict__ z_in,
    const float* __restrict__ w_in,
    const float* __restrict__ b_in,
    float* __restrict__ out,
    int B)
{
    int i = blockIdx.x * blockDim.x + threadIdx.x;
    if (i >= B) return;

    // w: [B,4,3,3] -> 36 floats = 9 float4 per element, 16B-aligned (144B stride)
    const float4* wv = reinterpret_cast<const float4*>(w_in) + (size_t)i * 9;
    // b: [B,4,3] -> 12 floats = 3 float4 per element, 16B-aligned (48B stride)
    const float4* bv = reinterpret_cast<const float4*>(b_in) + (size_t)i * 3;

    float wl[36];
#pragma unroll
    for (int j = 0; j < 9; ++j) {
        float4 t = wv[j];
        wl[j * 4 + 0] = t.x;
        wl[j * 4 + 1] = t.y;
        wl[j * 4 + 2] = t.z;
        wl[j * 4 + 3] = t.w;
    }

    float bl[12];
#pragma unroll
    for (int j = 0; j < 3; ++j) {
        float4 t = bv[j];
        bl[j * 4 + 0] = t.x;
        bl[j * 4 + 1] = t.y;
        bl[j * 4 + 2] = t.z;
        bl[j * 4 + 3] = t.w;
    }

    float z0 = z_in[(size_t)i * 3 + 0];
    float z1 = z_in[(size_t)i * 3 + 1];
    float z2 = z_in[(size_t)i * 3 + 2];

    float ld = 0.0f;

#pragma unroll
    for (int k = 0; k < 4; ++k) {
        const int o = k * 9;
        const float w00 = wl[o + 0], w01 = wl[o + 1], w02 = wl[o + 2];
        const float w10 = wl[o + 3], w11 = wl[o + 4], w12 = wl[o + 5];
        const float w20 = wl[o + 6], w21 = wl[o + 7], w22 = wl[o + 8];

        // positive diagonal used inside W = L @ diag(d) @ U
        const float d0 = fabsf(w00) + FLOW_EPS;
        const float d1 = fabsf(w11) + FLOW_EPS;
        const float d2 = fabsf(w22) + FLOW_EPS;

        // t = z @ L   (L unit lower-triangular from w)
        const float t0 = fmaf(z2, w20, fmaf(z1, w10, z0));
        const float t1 = fmaf(z2, w21, z1);
        const float t2 = z2;

        // s = t * d   (diagonal scaling)
        const float s0 = t0 * d0;
        const float s1 = t1 * d1;
        const float s2 = t2 * d2;

        // z = s @ U + b   (U unit upper-triangular from w)
        z0 = s0 + bl[k * 3 + 0];
        z1 = fmaf(s0, w01, s1) + bl[k * 3 + 1];
        z2 = fmaf(s0, w02, fmaf(s1, w12, s2)) + bl[k * 3 + 2];

        // log-det term: log|EPS + diag| (as written in the TF source — raw diag!)
        ld += __logf(fabsf(FLOW_EPS + w00))
            + __logf(fabsf(FLOW_EPS + w11))
            + __logf(fabsf(FLOW_EPS + w22));
    }

    // out: [B, 4] = {z0, z1, z2, log_det}, 16B-aligned float4 store
    reinterpret_cast<float4*>(out)[i] = make_float4(z0, z1, z2, ld);
}

extern "C" void kernel_launch(void* const* d_in, const int* in_sizes, int n_in,
                              void* d_out, int out_size, void* d_ws, size_t ws_size,
                              hipStream_t stream) {
    const float* z = (const float*)d_in[0];
    const float* w = (const float*)d_in[1];
    const float* b = (const float*)d_in[2];
    float* out = (float*)d_out;

    const int B = in_sizes[0] / 3;  // z is [B,3]
    const int block = 256;
    const int grid = (B + block - 1) / block;

    graphflow_kernel<<<grid, block, 0, stream>>>(z, w, b, out, B);
}

// Round 2
// 89.432 us; speedup vs baseline: 1.1290x; 1.1290x over previous
//
#include <hip/hip_runtime.h>

#define FLOW_EPS 0.1f

// XOR involution used on both the global-source index (pre-swizzle) and the
// LDS read index: loc(f) = f ^ ((f>>4)&7). Bijective on any multiple-of-8
// range (only touches bits 0-2, keyed off bits 4-6). Makes the per-thread
// stride-9 float4 reads bank-balanced while keeping global_load_lds sources
// a within-1KiB permutation (fully coalesced).
#define SWZ(f) ((f) ^ (((f) >> 4) & 7))

__device__ __forceinline__ void flow_compute(const float* wl, const float* bl,
                                             float& z0, float& z1, float& z2,
                                             float& ld)
{
#pragma unroll
    for (int k = 0; k < 4; ++k) {
        const int o = k * 9;
        const float w00 = wl[o + 0], w01 = wl[o + 1], w02 = wl[o + 2];
        const float w10 = wl[o + 3], w11 = wl[o + 4], w12 = wl[o + 5];
        const float w20 = wl[o + 6], w21 = wl[o + 7], w22 = wl[o + 8];

        const float d0 = fabsf(w00) + FLOW_EPS;
        const float d1 = fabsf(w11) + FLOW_EPS;
        const float d2 = fabsf(w22) + FLOW_EPS;

        // t = z @ L (unit lower-tri)
        const float t0 = fmaf(z2, w20, fmaf(z1, w10, z0));
        const float t1 = fmaf(z2, w21, z1);
        const float t2 = z2;
        // s = t * d
        const float s0 = t0 * d0;
        const float s1 = t1 * d1;
        const float s2 = t2 * d2;
        // z = s @ U + b (unit upper-tri)
        z0 = s0 + bl[k * 3 + 0];
        z1 = fmaf(s0, w01, s1) + bl[k * 3 + 1];
        z2 = fmaf(s0, w02, fmaf(s1, w12, s2)) + bl[k * 3 + 2];

        // log|EPS + raw diag| — exactly as the TF source
        ld += __logf(fabsf(FLOW_EPS + w00))
            + __logf(fabsf(FLOW_EPS + w11))
            + __logf(fabsf(FLOW_EPS + w22));
    }
}

// Main kernel: full 256-thread blocks only (grid = B/256).
// Per-wave LDS staging: each wave stages its own 64 elements.
__global__ __launch_bounds__(256) void graphflow_kernel(
    const float* __restrict__ z_in,
    const float* __restrict__ w_in,
    const float* __restrict__ b_in,
    float* __restrict__ out)
{
    __shared__ float4 lds_w[4][576];  // 9 float4 x 64 el per wave
    __shared__ float4 lds_b[4][192];  // 3 float4 x 64 el per wave

    const int tid  = threadIdx.x;
    const int wave = tid >> 6;
    const int lane = tid & 63;

    const long long blockBase = (long long)blockIdx.x * 256;
    const long long waveBase  = blockBase + (long long)wave * 64;

    const float4* wg = reinterpret_cast<const float4*>(w_in) + waveBase * 9;
    const float4* bg = reinterpret_cast<const float4*>(b_in) + waveBase * 3;

    // stage w: 9 wave-wide 1KiB DMA ops, swizzled source -> linear LDS dest
#pragma unroll
    for (int j = 0; j < 9; ++j) {
        const int q = j * 64 + lane;
        __builtin_amdgcn_global_load_lds(
            (const __attribute__((address_space(1))) void*)(wg + SWZ(q)),
            (__attribute__((address_space(3))) void*)(&lds_w[wave][j * 64]),
            16, 0, 0);
    }
    // stage b: 3 wave-wide DMA ops
#pragma unroll
    for (int j = 0; j < 3; ++j) {
        const int q = j * 64 + lane;
        __builtin_amdgcn_global_load_lds(
            (const __attribute__((address_space(1))) void*)(bg + SWZ(q)),
            (__attribute__((address_space(3))) void*)(&lds_b[wave][j * 64]),
            16, 0, 0);
    }

    // z: direct coalesced scalar loads (12 B/el, dense)
    const long long i = blockBase + tid;
    float z0 = z_in[i * 3 + 0];
    float z1 = z_in[i * 3 + 1];
    float z2 = z_in[i * 3 + 2];

    __syncthreads();  // drains vmcnt(0): LDS populated

    // gather this thread's w (9 float4) and b (3 float4), swizzled reads
    float wl[36];
#pragma unroll
    for (int s = 0; s < 9; ++s) {
        const int f = 9 * lane + s;
        const float4 t = lds_w[wave][SWZ(f)];
        wl[4 * s + 0] = t.x; wl[4 * s + 1] = t.y;
        wl[4 * s + 2] = t.z; wl[4 * s + 3] = t.w;
    }
    float bl[12];
#pragma unroll
    for (int s = 0; s < 3; ++s) {
        const int f = 3 * lane + s;
        const float4 t = lds_b[wave][SWZ(f)];
        bl[4 * s + 0] = t.x; bl[4 * s + 1] = t.y;
        bl[4 * s + 2] = t.z; bl[4 * s + 3] = t.w;
    }

    float ld = 0.0f;
    flow_compute(wl, bl, z0, z1, z2, ld);

    reinterpret_cast<float4*>(out)[i] = make_float4(z0, z1, z2, ld);
}

// Tail kernel (only if B % 256 != 0): direct-load path, one thread per element.
__global__ __launch_bounds__(256) void graphflow_tail_kernel(
    const float* __restrict__ z_in,
    const float* __restrict__ w_in,
    const float* __restrict__ b_in,
    float* __restrict__ out,
    int start, int B)
{
    const int i = start + blockIdx.x * blockDim.x + threadIdx.x;
    if (i >= B) return;

    const float4* wv = reinterpret_cast<const float4*>(w_in) + (size_t)i * 9;
    const float4* bv = reinterpret_cast<const float4*>(b_in) + (size_t)i * 3;

    float wl[36];
#pragma unroll
    for (int j = 0; j < 9; ++j) {
        float4 t = wv[j];
        wl[j * 4 + 0] = t.x; wl[j * 4 + 1] = t.y;
        wl[j * 4 + 2] = t.z; wl[j * 4 + 3] = t.w;
    }
    float bl[12];
#pragma unroll
    for (int j = 0; j < 3; ++j) {
        float4 t = bv[j];
        bl[j * 4 + 0] = t.x; bl[j * 4 + 1] = t.y;
        bl[j * 4 + 2] = t.z; bl[j * 4 + 3] = t.w;
    }

    float z0 = z_in[(size_t)i * 3 + 0];
    float z1 = z_in[(size_t)i * 3 + 1];
    float z2 = z_in[(size_t)i * 3 + 2];
    float ld = 0.0f;
    flow_compute(wl, bl, z0, z1, z2, ld);
    reinterpret_cast<float4*>(out)[i] = make_float4(z0, z1, z2, ld);
}

extern "C" void kernel_launch(void* const* d_in, const int* in_sizes, int n_in,
                              void* d_out, int out_size, void* d_ws, size_t ws_size,
                              hipStream_t stream) {
    const float* z = (const float*)d_in[0];
    const float* w = (const float*)d_in[1];
    const float* b = (const float*)d_in[2];
    float* out = (float*)d_out;

    const int B = in_sizes[0] / 3;      // z is [B,3]
    const int full_blocks = B / 256;    // B = 2,097,152 -> 8192 exact

    if (full_blocks > 0) {
        graphflow_kernel<<<full_blocks, 256, 0, stream>>>(z, w, b, out);
    }
    const int rem_start = full_blocks * 256;
    const int rem = B - rem_start;
    if (rem > 0) {
        graphflow_tail_kernel<<<(rem + 255) / 256, 256, 0, stream>>>(
            z, w, b, out, rem_start, B);
    }
}